// Round 4
// baseline (152.343 us; speedup 1.0000x reference)
//
#include <hip/hip_runtime.h>
#include <hip/hip_bf16.h>

// Expand: repeat each x[b,i,:] dimensions[b,i] times along axis 1, left-packed,
// zero-padded to T = max_b sum(dims[b,:]).
// Shapes fixed by setup_inputs(): B=16, S=1024, D=384.

#define S_TOKENS 1024
#define B_BATCH 16
#define QVEC 96   // D/4 float4 per row (D=384)

typedef float f4 __attribute__((ext_vector_type(4)));

// --- Kernel 1: per-batch scan of dims (wave-shuffle) + scatter row->src map ---
// idx[b*T + t] = absolute source row (b*S + i) for output position t, or -1 pad.
__global__ void prep_kernel(const int* __restrict__ dims, int* __restrict__ idx,
                            int T) {
    __shared__ int wsum[16];   // per-wave totals
    __shared__ int wexc[16];   // per-wave exclusive offsets
    const int b    = blockIdx.x;
    const int tid  = threadIdx.x;
    const int lane = tid & 63;
    const int wid  = tid >> 6;

    const int v = dims[b * S_TOKENS + tid];
    // inclusive scan within wave (64 lanes)
    int inc = v;
#pragma unroll
    for (int d = 1; d < 64; d <<= 1) {
        int u = __shfl_up(inc, d, 64);
        if (lane >= d) inc += u;
    }
    if (lane == 63) wsum[wid] = inc;
    __syncthreads();
    if (tid < 16) {
        int w = wsum[tid];
        int incw = w;
#pragma unroll
        for (int d = 1; d < 16; d <<= 1) {
            int u = __shfl_up(incw, d, 16);
            if (tid >= d) incw += u;
        }
        wexc[tid] = incw - w;   // exclusive wave offset
    }
    __syncthreads();

    const int end   = inc + wexc[wid];
    const int start = end - v;
    const int total = wexc[15] + wsum[15];

    int* __restrict__ idx_b = idx + b * T;
    const int src = b * S_TOKENS + tid;
    for (int t = start; t < end; ++t) idx_b[t] = src;               // <=9 writes/thread
    for (int t = total + tid; t < T; t += S_TOKENS) idx_b[t] = -1;  // pad tail
}

// --- Kernel 2: 32 B per thread (2 coalesced float4); map lookup + gather ---
__global__ void expand_kernel(const f4* __restrict__ x4,
                              const int* __restrict__ idx,
                              f4* __restrict__ out4,
                              int n4) {
    const int base = blockIdx.x * 512 + threadIdx.x;
#pragma unroll
    for (int half = 0; half < 2; ++half) {
        const int k = base + half * 256;
        if (k < n4) {
            int row = k / QVEC;            // compile-time magic-mul
            int q   = k - row * QVEC;
            int src = idx[row];            // consecutive lanes share -> L1 broadcast
            f4 val = (f4)(0.f, 0.f, 0.f, 0.f);
            if (src >= 0) val = x4[src * QVEC + q];
            __builtin_nontemporal_store(val, &out4[k]);
        }
    }
}

extern "C" void kernel_launch(void* const* d_in, const int* in_sizes, int n_in,
                              void* d_out, int out_size, void* d_ws, size_t ws_size,
                              hipStream_t stream) {
    const float* x    = (const float*)d_in[0];   // [B, S, D] fp32
    const int*   dims = (const int*)d_in[1];     // [B, S] int32
    float*       out  = (float*)d_out;           // [B, T, D] fp32

    const int D = in_sizes[0] / in_sizes[1];     // 384
    const int T = out_size / (B_BATCH * D);      // max total length (~4700)

    int* idx = (int*)d_ws;                       // B*T ints (~300 KB) in workspace

    prep_kernel<<<B_BATCH, S_TOKENS, 0, stream>>>(dims, idx, T);

    const int n4 = out_size / 4;
    const int grid = (n4 + 511) / 512;           // 512 float4 per block
    expand_kernel<<<grid, 256, 0, stream>>>((const f4*)x, idx, (f4*)out, n4);
}

// Round 5
// 141.733 us; speedup vs baseline: 1.0749x; 1.0749x over previous
//
#include <hip/hip_runtime.h>
#include <hip/hip_bf16.h>

// Expand: repeat each x[b,i,:] dimensions[b,i] times along axis 1, left-packed,
// zero-padded to T = max_b sum(dims[b,:]).
// Shapes fixed by setup_inputs(): B=16, S=1024, D=384.
// Source-centric: one wave per source token; replicated rows are CONTIGUOUS
// in the output, so stores are pure sequential streams (no gather, no idx map).

#define S_TOKENS 1024
#define B_BATCH 16
#define QVEC 96   // D/4 float4 per row (D=384)
#define TOK_BLOCKS (B_BATCH * S_TOKENS / 4)  // 4096: 4 waves/block, 1 token/wave
#define PAD_BLOCKS 64                        // 4 blocks per batch for tail zeros

typedef float f4 __attribute__((ext_vector_type(4)));

// --- Kernel 1: per-batch inclusive scan of dims -> csum [B,S] ---
__global__ void scan_kernel(const int* __restrict__ dims, int* __restrict__ csum) {
    __shared__ int wsum[16];
    __shared__ int wexc[16];
    const int b    = blockIdx.x;
    const int tid  = threadIdx.x;
    const int lane = tid & 63;
    const int wid  = tid >> 6;

    const int v = dims[b * S_TOKENS + tid];
    int inc = v;
#pragma unroll
    for (int d = 1; d < 64; d <<= 1) {
        int u = __shfl_up(inc, d, 64);
        if (lane >= d) inc += u;
    }
    if (lane == 63) wsum[wid] = inc;
    __syncthreads();
    if (tid < 16) {
        int w = wsum[tid];
        int incw = w;
#pragma unroll
        for (int d = 1; d < 16; d <<= 1) {
            int u = __shfl_up(incw, d, 16);
            if (tid >= d) incw += u;
        }
        wexc[tid] = incw - w;
    }
    __syncthreads();
    csum[b * S_TOKENS + tid] = inc + wexc[wid];
}

// --- Kernel 2: replicate (token blocks) + zero-pad tail (pad blocks) ---
__global__ void expand_kernel(const f4* __restrict__ x4,
                              const int* __restrict__ csum,
                              f4* __restrict__ out4, int T) {
    const int blk = blockIdx.x;
    if (blk < TOK_BLOCKS) {
        const int wid   = threadIdx.x >> 6;       // wave in block: 0..3
        const int lane  = threadIdx.x & 63;
        const int token = blk * 4 + wid;          // 0..16383
        const int b     = token >> 10;
        const int i     = token & (S_TOKENS - 1);
        const int* __restrict__ c = csum + b * S_TOKENS;
        const int end   = c[i];                   // wave-uniform broadcast loads
        const int start = (i == 0) ? 0 : c[i - 1];
        const int rep   = end - start;
        if (rep <= 0) return;

        const f4* __restrict__ row = x4 + (size_t)(b * S_TOKENS + i) * QVEC;
        f4 v0 = row[lane];                        // q = 0..63
        f4 v1 = (f4)(0.f, 0.f, 0.f, 0.f);
        if (lane < 32) v1 = row[64 + lane];       // q = 64..95

        f4* dst = out4 + ((size_t)b * T + start) * QVEC;
        for (int r = 0; r < rep; ++r, dst += QVEC) {   // contiguous 1.5 KB rows
            dst[lane] = v0;
            if (lane < 32) dst[64 + lane] = v1;
        }
    } else {
        // zero-pad: rows [total, T) of batch b, flat contiguous fill
        const int p   = blk - TOK_BLOCKS;         // 0..63
        const int b   = p >> 2;
        const int sub = p & 3;
        const int total = csum[b * S_TOKENS + S_TOKENS - 1];
        const int n = (T - total) * QVEC;         // f4 count of pad region
        f4* __restrict__ dst = out4 + ((size_t)b * T + total) * QVEC;
        const f4 z = (f4)(0.f, 0.f, 0.f, 0.f);
        for (int j = sub * 256 + threadIdx.x; j < n; j += 4 * 256)
            dst[j] = z;
    }
}

extern "C" void kernel_launch(void* const* d_in, const int* in_sizes, int n_in,
                              void* d_out, int out_size, void* d_ws, size_t ws_size,
                              hipStream_t stream) {
    const float* x    = (const float*)d_in[0];   // [B, S, D] fp32
    const int*   dims = (const int*)d_in[1];     // [B, S] int32
    float*       out  = (float*)d_out;           // [B, T, D] fp32

    const int D = in_sizes[0] / in_sizes[1];     // 384
    const int T = out_size / (B_BATCH * D);      // max total length (~4800)

    int* csum = (int*)d_ws;                      // B*S ints = 64 KB

    scan_kernel<<<B_BATCH, S_TOKENS, 0, stream>>>(dims, csum);

    expand_kernel<<<TOK_BLOCKS + PAD_BLOCKS, 256, 0, stream>>>(
        (const f4*)x, csum, (f4*)out, T);
}

// Round 6
// 140.367 us; speedup vs baseline: 1.0853x; 1.0097x over previous
//
#include <hip/hip_runtime.h>
#include <hip/hip_bf16.h>

// Expand: repeat each x[b,i,:] dimensions[b,i] times along axis 1, left-packed,
// zero-padded to T = max_b sum(dims[b,:]).
// Shapes fixed by setup_inputs(): B=16, S=1024, D=384.
// Source-centric, one token per 64-thread block: wave==workgroup so early
// finishers release their SIMD slot immediately (no block-retire imbalance).

#define S_TOKENS 1024
#define B_BATCH 16
#define QVEC 96   // D/4 float4 per row (D=384)
#define TOK_BLOCKS (B_BATCH * S_TOKENS)   // 16384 blocks, 1 token each
#define PAD_BLOCKS 256                    // 16 per batch for tail zeros

typedef float f4 __attribute__((ext_vector_type(4)));

// --- Kernel 1: per-batch inclusive scan of dims -> csum [B,S] ---
__global__ void scan_kernel(const int* __restrict__ dims, int* __restrict__ csum) {
    __shared__ int wsum[16];
    __shared__ int wexc[16];
    const int b    = blockIdx.x;
    const int tid  = threadIdx.x;
    const int lane = tid & 63;
    const int wid  = tid >> 6;

    const int v = dims[b * S_TOKENS + tid];
    int inc = v;
#pragma unroll
    for (int d = 1; d < 64; d <<= 1) {
        int u = __shfl_up(inc, d, 64);
        if (lane >= d) inc += u;
    }
    if (lane == 63) wsum[wid] = inc;
    __syncthreads();
    if (tid < 16) {
        int w = wsum[tid];
        int incw = w;
#pragma unroll
        for (int d = 1; d < 16; d <<= 1) {
            int u = __shfl_up(incw, d, 16);
            if (tid >= d) incw += u;
        }
        wexc[tid] = incw - w;
    }
    __syncthreads();
    csum[b * S_TOKENS + tid] = inc + wexc[wid];
}

// --- Kernel 2: replicate (token blocks) + zero-pad tail (pad blocks) ---
__global__ __launch_bounds__(64) void expand_kernel(const f4* __restrict__ x4,
                              const int* __restrict__ csum,
                              f4* __restrict__ out4, int T) {
    const int blk = blockIdx.x;
    if (blk < TOK_BLOCKS) {
        const int lane = threadIdx.x;             // 0..63
        const int b    = blk >> 10;
        const int i    = blk & (S_TOKENS - 1);
        const int* __restrict__ c = csum + b * S_TOKENS;
        const int end   = c[i];                   // wave-uniform broadcast loads
        const int start = (i == 0) ? 0 : c[i - 1];
        const int rep   = end - start;
        if (rep <= 0) return;                     // slot freed immediately

        const f4* __restrict__ row = x4 + (size_t)(b * S_TOKENS + i) * QVEC;
        f4 v0 = row[lane];                        // q = 0..63
        f4 v1 = (f4)(0.f, 0.f, 0.f, 0.f);
        if (lane < 32) v1 = row[64 + lane];       // q = 64..95

        f4* dst = out4 + ((size_t)b * T + start) * QVEC;
        for (int r = 0; r < rep; ++r, dst += QVEC) {   // contiguous 1.5 KB rows
            dst[lane] = v0;
            if (lane < 32) dst[64 + lane] = v1;
        }
    } else {
        // zero-pad: rows [total, T) of batch b, flat contiguous fill
        const int p   = blk - TOK_BLOCKS;         // 0..255
        const int b   = p >> 4;
        const int sub = p & 15;
        const int total = csum[b * S_TOKENS + S_TOKENS - 1];
        const int n = (T - total) * QVEC;         // f4 count of pad region
        f4* __restrict__ dst = out4 + ((size_t)b * T + total) * QVEC;
        const f4 z = (f4)(0.f, 0.f, 0.f, 0.f);
        for (int j = sub * 64 + threadIdx.x; j < n; j += 16 * 64)
            dst[j] = z;
    }
}

extern "C" void kernel_launch(void* const* d_in, const int* in_sizes, int n_in,
                              void* d_out, int out_size, void* d_ws, size_t ws_size,
                              hipStream_t stream) {
    const float* x    = (const float*)d_in[0];   // [B, S, D] fp32
    const int*   dims = (const int*)d_in[1];     // [B, S] int32
    float*       out  = (float*)d_out;           // [B, T, D] fp32

    const int D = in_sizes[0] / in_sizes[1];     // 384
    const int T = out_size / (B_BATCH * D);      // max total length (~4800)

    int* csum = (int*)d_ws;                      // B*S ints = 64 KB

    scan_kernel<<<B_BATCH, S_TOKENS, 0, stream>>>(dims, csum);

    expand_kernel<<<TOK_BLOCKS + PAD_BLOCKS, 64, 0, stream>>>(
        (const f4*)x, csum, (f4*)out, T);
}

// Round 7
// 140.179 us; speedup vs baseline: 1.0868x; 1.0013x over previous
//
#include <hip/hip_runtime.h>
#include <hip/hip_bf16.h>

// Expand: repeat each x[b,i,:] dimensions[b,i] times along axis 1, left-packed,
// zero-padded to T = max_b sum(dims[b,:]).
// Shapes fixed by setup_inputs(): B=16, S=1024, D=384.
// Single fused kernel: each 64-thread block (one wave) owns one source token,
// computes its own prefix sum from dims (64 KB, L2-resident) via masked
// chunk-sum + shfl_xor reduce, then streams rep contiguous 1.5 KB rows.
// No scan kernel, no csum buffer, no launch gap.

#define S_TOKENS 1024
#define B_BATCH 16
#define QVEC 96   // D/4 float4 per row (D=384)
#define TOK_BLOCKS (B_BATCH * S_TOKENS)   // 16384 blocks, 1 token each
#define PAD_BLOCKS 256                    // 16 per batch for tail zeros

typedef float f4 __attribute__((ext_vector_type(4)));
typedef int   i4 __attribute__((ext_vector_type(4)));

__global__ __launch_bounds__(64) void expand_kernel(const f4* __restrict__ x4,
                                                    const int* __restrict__ dims,
                                                    f4* __restrict__ out4, int T) {
    const int blk  = blockIdx.x;
    const int lane = threadIdx.x;          // 0..63

    if (blk < TOK_BLOCKS) {
        const int b = blk >> 10;
        const int i = blk & (S_TOKENS - 1);
        const int* __restrict__ db = dims + b * S_TOKENS;
        const i4* __restrict__ d4 = (const i4*)db;   // 256 int4 per batch

        // lane sums its 16-int chunk, masked by global index j <= i
        int s_le = 0;
        const int base = lane * 16;
#pragma unroll
        for (int c = 0; c < 4; ++c) {
            i4 v = d4[lane * 4 + c];
#pragma unroll
            for (int e = 0; e < 4; ++e) {
                int j = base + c * 4 + e;
                s_le += (j <= i) ? v[e] : 0;
            }
        }
#pragma unroll
        for (int d = 1; d < 64; d <<= 1)
            s_le += __shfl_xor(s_le, d, 64);

        const int rep   = db[i];           // wave-uniform broadcast load
        const int start = s_le - rep;      // exclusive prefix
        if (rep <= 0) return;              // wave slot freed immediately

        const f4* __restrict__ row = x4 + (size_t)(b * S_TOKENS + i) * QVEC;
        f4 v0 = row[lane];                 // q = 0..63
        f4 v1 = (f4)(0.f, 0.f, 0.f, 0.f);
        if (lane < 32) v1 = row[64 + lane];   // q = 64..95

        f4* dst = out4 + ((size_t)b * T + start) * QVEC;
        for (int r = 0; r < rep; ++r, dst += QVEC) {   // contiguous 1.5 KB rows
            dst[lane] = v0;
            if (lane < 32) dst[64 + lane] = v1;
        }
    } else {
        // zero-pad rows [total, T) of batch b: flat contiguous fill
        const int p   = blk - TOK_BLOCKS;  // 0..255
        const int b   = p >> 4;
        const int sub = p & 15;
        const i4* __restrict__ d4 = (const i4*)(dims + b * S_TOKENS);

        int s_all = 0;
#pragma unroll
        for (int c = 0; c < 4; ++c) {
            i4 v = d4[lane * 4 + c];
            s_all += v[0] + v[1] + v[2] + v[3];
        }
#pragma unroll
        for (int d = 1; d < 64; d <<= 1)
            s_all += __shfl_xor(s_all, d, 64);

        const int total = s_all;
        const int n = (T - total) * QVEC;  // f4 count of pad region
        f4* __restrict__ dst = out4 + ((size_t)b * T + total) * QVEC;
        const f4 z = (f4)(0.f, 0.f, 0.f, 0.f);
        for (int j = sub * 64 + lane; j < n; j += 16 * 64)
            dst[j] = z;
    }
}

extern "C" void kernel_launch(void* const* d_in, const int* in_sizes, int n_in,
                              void* d_out, int out_size, void* d_ws, size_t ws_size,
                              hipStream_t stream) {
    const float* x    = (const float*)d_in[0];   // [B, S, D] fp32
    const int*   dims = (const int*)d_in[1];     // [B, S] int32
    float*       out  = (float*)d_out;           // [B, T, D] fp32

    const int D = in_sizes[0] / in_sizes[1];     // 384
    const int T = out_size / (B_BATCH * D);      // max total length (~4800)

    expand_kernel<<<TOK_BLOCKS + PAD_BLOCKS, 64, 0, stream>>>(
        (const f4*)x, dims, (f4*)out, T);
}